// Round 14
// baseline (904.579 us; speedup 1.0000x reference)
//
#include <hip/hip_runtime.h>
#include <hip/hip_bf16.h>
#include <math.h>

#define LN_EPS 1e-5f
#define ATT_SCALE 0.125f   // 64^-0.5

typedef __bf16 bf16x8 __attribute__((ext_vector_type(8)));
typedef float f32x4 __attribute__((ext_vector_type(4)));

__device__ __forceinline__ unsigned short f2bf(float f){
  unsigned int u = __builtin_bit_cast(unsigned int, f);
  u += 0x7fffu + ((u >> 16) & 1u);
  return (unsigned short)(u >> 16);
}
__device__ __forceinline__ float bfbits2f(unsigned int lo16){
  return __builtin_bit_cast(float, lo16 << 16);
}

// ---------------- LayerNorm: fp32 in -> bf16 out (row = 1024) ----------------
__global__ __launch_bounds__(256) void ln_kernel(
    const float* __restrict__ X, const float* __restrict__ g,
    const float* __restrict__ b, unsigned short* __restrict__ H)
{
  __shared__ float red[4];
  int row = blockIdx.x, t = threadIdx.x;
  const float4 xv = ((const float4*)(X + (size_t)row*1024))[t];
  float s = xv.x + xv.y + xv.z + xv.w;
  #pragma unroll
  for (int o=32;o;o>>=1) s += __shfl_down(s,o);
  if ((t&63)==0) red[t>>6] = s;
  __syncthreads();
  float mu = (red[0]+red[1]+red[2]+red[3]) * (1.f/1024.f);
  __syncthreads();
  float dx = xv.x-mu, dy = xv.y-mu, dz = xv.z-mu, dw = xv.w-mu;
  float s2 = dx*dx+dy*dy+dz*dz+dw*dw;
  #pragma unroll
  for (int o=32;o;o>>=1) s2 += __shfl_down(s2,o);
  if ((t&63)==0) red[t>>6] = s2;
  __syncthreads();
  float var = (red[0]+red[1]+red[2]+red[3]) * (1.f/1024.f);
  float rs = rsqrtf(var + LN_EPS);
  const float4 gv = ((const float4*)g)[t];
  const float4 bv = ((const float4*)b)[t];
  ushort4 o4;
  o4.x = f2bf(dx*rs*gv.x + bv.x);
  o4.y = f2bf(dy*rs*gv.y + bv.y);
  o4.z = f2bf(dz*rs*gv.z + bv.z);
  o4.w = f2bf(dw*rs*gv.w + bv.w);
  ((ushort4*)(H + (size_t)row*1024))[t] = o4;
}

// -- split-K reduce (bf16 partials, +bias,scale,residual) + optional fused LN -
template<int SK, int DO_LN>
__global__ __launch_bounds__(256) void redln_kernel(
    const unsigned short* __restrict__ P, float* __restrict__ X,
    const float* __restrict__ bias, const float* __restrict__ scale,
    const float* __restrict__ g, const float* __restrict__ b,
    unsigned short* __restrict__ H)
{
  __shared__ float red[4];
  int row = blockIdx.x, t = threadIdx.x;
  size_t off = (size_t)row*1024 + t*4;
  float4 xv = *(const float4*)(X + off);
  float4 pv;
  {
    uint2 u = *(const uint2*)(P + off);
    pv.x = bfbits2f(u.x & 0xffffu); pv.y = bfbits2f(u.x >> 16);
    pv.z = bfbits2f(u.y & 0xffffu); pv.w = bfbits2f(u.y >> 16);
  }
  #pragma unroll
  for (int c=1;c<SK;c++){
    uint2 u = *(const uint2*)(P + (size_t)c*2048*1024 + off);
    pv.x += bfbits2f(u.x & 0xffffu); pv.y += bfbits2f(u.x >> 16);
    pv.z += bfbits2f(u.y & 0xffffu); pv.w += bfbits2f(u.y >> 16);
  }
  const float4 bv = ((const float4*)bias)[t];
  const float4 sv = ((const float4*)scale)[t];
  xv.x += (pv.x+bv.x)*sv.x;
  xv.y += (pv.y+bv.y)*sv.y;
  xv.z += (pv.z+bv.z)*sv.z;
  xv.w += (pv.w+bv.w)*sv.w;
  *(float4*)(X + off) = xv;
  if (DO_LN){
    float s = xv.x + xv.y + xv.z + xv.w;
    #pragma unroll
    for (int o=32;o;o>>=1) s += __shfl_down(s,o);
    if ((t&63)==0) red[t>>6] = s;
    __syncthreads();
    float mu = (red[0]+red[1]+red[2]+red[3]) * (1.f/1024.f);
    __syncthreads();
    float dx = xv.x-mu, dy = xv.y-mu, dz = xv.z-mu, dw = xv.w-mu;
    float s2 = dx*dx+dy*dy+dz*dz+dw*dw;
    #pragma unroll
    for (int o=32;o;o>>=1) s2 += __shfl_down(s2,o);
    if ((t&63)==0) red[t>>6] = s2;
    __syncthreads();
    float var = (red[0]+red[1]+red[2]+red[3]) * (1.f/1024.f);
    float rs = rsqrtf(var + LN_EPS);
    const float4 gv = ((const float4*)g)[t];
    const float4 lbv = ((const float4*)b)[t];
    ushort4 o4;
    o4.x = f2bf(dx*rs*gv.x + lbv.x);
    o4.y = f2bf(dy*rs*gv.y + lbv.y);
    o4.z = f2bf(dz*rs*gv.z + lbv.z);
    o4.w = f2bf(dw*rs*gv.w + lbv.w);
    ((ushort4*)(H + (size_t)row*1024))[t] = o4;
  }
}

// -- transpose + fp32->bf16 convert, all layers batched: W (L,KxN) -> WT (L,NxK)
__global__ __launch_bounds__(256) void trc_kernel(
    const float* __restrict__ W, unsigned short* __restrict__ WT, int K, int N)
{
  __shared__ float tile[64][65];
  const float* Wz = W + (size_t)blockIdx.z*K*N;
  unsigned short* WTz = WT + (size_t)blockIdx.z*K*N;
  int n0 = blockIdx.x*64, k0 = blockIdx.y*64;
  int t = threadIdx.x;
  int tx = t & 63, ty = t >> 6;
  #pragma unroll
  for (int p=0;p<16;p++){
    int r = ty*16+p;
    tile[r][tx] = Wz[(size_t)(k0+r)*N + n0 + tx];
  }
  __syncthreads();
  int kc = t & 31, tb = t >> 5;
  #pragma unroll
  for (int p=0;p<8;p++){
    int nr = tb + p*8;
    unsigned int lo = f2bf(tile[2*kc][nr]);
    unsigned int hi = f2bf(tile[2*kc+1][nr]);
    ((unsigned int*)(WTz + (size_t)(n0+nr)*K + k0))[kc] = lo | (hi<<16);
  }
}

// --- W1 transpose, a/g 16-col interleave, batched: W1 (L,1024x8192) -> WT ----
__global__ __launch_bounds__(256) void trc_w1_kernel(
    const float* __restrict__ W, unsigned short* __restrict__ WT)
{
  __shared__ float tile[64][65];
  const float* Wz = W + (size_t)blockIdx.z*1024*8192;
  unsigned short* WTz = WT + (size_t)blockIdx.z*1024*8192;
  int n0 = blockIdx.x*64, k0 = blockIdx.y*64;
  int ca = (n0>>5)*16;
  int t = threadIdx.x;
  int tx = t & 63, ty = t >> 6;
  #pragma unroll
  for (int p=0;p<16;p++){
    int r = ty*16+p;
    int col = (tx < 32) ? (ca + tx) : (ca + 4064 + tx);
    tile[r][tx] = Wz[(size_t)(k0+r)*8192 + col];
  }
  __syncthreads();
  int kc = t & 31, tb = t >> 5;
  #pragma unroll
  for (int p=0;p<8;p++){
    int nr = tb + p*8;
    int rr = nr & 31;
    int vcol = (nr>>5)*16 + (rr&15) + ((rr>>4)<<5);
    unsigned int lo = f2bf(tile[2*kc][vcol]);
    unsigned int hi = f2bf(tile[2*kc+1][vcol]);
    ((unsigned int*)(WTz + (size_t)(n0+nr)*1024 + k0))[kc] = lo | (hi<<16);
  }
}

// ----------- bf16 MFMA GEMM, 128x128, BK=64, 2-phase double-buffer -----------
// MODE 0: Obf = A@B (bf16, ld N)
// MODE 3: split-K bf16 partials at Obf[z*M*N + ...]
// MODE 4: GEGLU epilogue (WT a/g-interleaved): Obf = a*gelu(g), ld 4096
// All epilogues LDS-bounced for coalesced uint4 stores.
template<int MODE, int SWZ>
__global__ __launch_bounds__(256) void gemm_bt(
    const unsigned short* __restrict__ A, const unsigned short* __restrict__ BT,
    int M, int N, int K,
    unsigned short* __restrict__ Obf,
    const float* __restrict__ bias)
{
  __shared__ unsigned short Asm[2][128*64];
  __shared__ unsigned short Bsm[2][128*64];
  int t = threadIdx.x;
  int lane = t & 63;
  int w = t >> 6, wm = w >> 1, wn = w & 1;

  int bn, bm;
  if (SWZ){
    int nwg = gridDim.x * gridDim.y;
    int wg = blockIdx.y * gridDim.x + blockIdx.x;
    int cpx = nwg >> 3;
    int swz = (wg & 7) * cpx + (wg >> 3);
    bn = swz % gridDim.x; bm = swz / gridDim.x;
  } else {
    bn = blockIdx.x; bm = blockIdx.y;
  }

  f32x4 acc[4][4] = {};
  int ktBeg = 0, ktEnd = K >> 6;
  if (MODE == 3){
    int per = (K >> 6) / gridDim.z;
    ktBeg = blockIdx.z * per;
    ktEnd = ktBeg + per;
  }

  int srow = t >> 3, ssc = t & 7;
  auto STAGE = [&](int kt, int buf){
    #pragma unroll
    for (int c=0;c<4;c++){
      int row = c*32 + srow;
      int gc = ssc ^ (row & 7);
      const unsigned short* sa = A  + (size_t)(bm*128 + row)*K + kt*64 + gc*8;
      const unsigned short* sb = BT + (size_t)(bn*128 + row)*K + kt*64 + gc*8;
      __builtin_amdgcn_global_load_lds(
        (const __attribute__((address_space(1))) unsigned int*)sa,
        (__attribute__((address_space(3))) unsigned int*)(&Asm[buf][(c*256 + (t & ~63))*8]),
        16, 0, 0);
      __builtin_amdgcn_global_load_lds(
        (const __attribute__((address_space(1))) unsigned int*)sb,
        (__attribute__((address_space(3))) unsigned int*)(&Bsm[buf][(c*256 + (t & ~63))*8]),
        16, 0, 0);
    }
  };

  STAGE(ktBeg, 0);
  __syncthreads();
  int cur = 0;
  for (int kt = ktBeg; kt < ktEnd; ++kt){
    if (kt + 1 < ktEnd) STAGE(kt + 1, cur ^ 1);
    #pragma unroll
    for (int kk=0;kk<2;kk++){
      bf16x8 aF[4], bF[4];
      #pragma unroll
      for (int m=0;m<4;m++){
        int row = wm*64 + m*16 + (lane&15);
        int ch = kk*4 + (lane>>4);
        aF[m] = *(const bf16x8*)&Asm[cur][row*64 + (ch ^ (row&7))*8];
      }
      #pragma unroll
      for (int n=0;n<4;n++){
        int row = wn*64 + n*16 + (lane&15);
        int ch = kk*4 + (lane>>4);
        bF[n] = *(const bf16x8*)&Bsm[cur][row*64 + (ch ^ (row&7))*8];
      }
      __builtin_amdgcn_s_setprio(1);
      #pragma unroll
      for (int m=0;m<4;m++)
        #pragma unroll
        for (int n=0;n<4;n++)
          acc[m][n] = __builtin_amdgcn_mfma_f32_16x16x32_bf16(aF[m], bF[n], acc[m][n], 0,0,0);
      __builtin_amdgcn_s_setprio(0);
    }
    __syncthreads();                 // includes vmcnt(0) drain: Asm/Bsm dead after
    cur ^= 1;
  }

  // ---- coalesced epilogue via LDS bounce (reuse Asm: 16384 shorts) ----
  unsigned short* ep = &Asm[0][0];
  int colg = lane & 15;
  int r0 = wm*64 + (lane>>4)*4;      // +m*16 +j
  if (MODE==4){
    float b1a[2], b1g[2];
    #pragma unroll
    for (int p=0;p<2;p++){
      int oc = (bn*4 + wn*2 + p)*16 + colg;
      b1a[p] = bias[oc];
      b1g[p] = bias[oc + 4096];
    }
    #pragma unroll
    for (int m=0;m<4;m++){
      #pragma unroll
      for (int p=0;p<2;p++){
        int cw = (wn*2 + p)*16 + colg;              // 0..63
        #pragma unroll
        for (int j=0;j<4;j++){
          float va = acc[m][2*p][j]   + b1a[p];
          float vg = acc[m][2*p+1][j] + b1g[p];
          float f = va * (0.5f * vg * (1.f + erff(vg * 0.70710678118f)));
          ep[(r0 + m*16 + j)*64 + cw] = f2bf(f);
        }
      }
    }
    __syncthreads();
    #pragma unroll
    for (int i=0;i<4;i++){
      int idx = i*256 + t;
      int row = idx >> 3, ch = idx & 7;
      *(uint4*)&Obf[(size_t)(bm*128+row)*4096 + bn*64 + ch*8] = *(const uint4*)&ep[row*64 + ch*8];
    }
    return;
  }
  #pragma unroll
  for (int m=0;m<4;m++)
    #pragma unroll
    for (int n=0;n<4;n++){
      int cw = wn*64 + n*16 + colg;                 // 0..127
      #pragma unroll
      for (int j=0;j<4;j++)
        ep[(r0 + m*16 + j)*128 + cw] = f2bf(acc[m][n][j]);
    }
  __syncthreads();
  size_t zoff = (MODE==3) ? (size_t)blockIdx.z*((size_t)M*N) : 0;
  #pragma unroll
  for (int i=0;i<8;i++){
    int idx = i*256 + t;
    int row = idx >> 4, ch = idx & 15;
    *(uint4*)&Obf[zoff + (size_t)(bm*128+row)*N + bn*128 + ch*8] = *(const uint4*)&ep[row*128 + ch*8];
  }
}

// ------------- V transpose: qkv (2048x3072) -> VT [16][64][2048] -------------
__global__ __launch_bounds__(256) void vtr_kernel(
    const unsigned short* __restrict__ qkv, unsigned short* __restrict__ VT)
{
  __shared__ unsigned int tile[64][33];
  int h = blockIdx.y;
  int n0 = blockIdx.x * 64;
  int t = threadIdx.x;
  #pragma unroll
  for (int p=0;p<8;p++){
    int idx = p*256 + t;
    int r = idx >> 5, c = idx & 31;
    tile[r][c] = *(const unsigned int*)(qkv + (size_t)(n0+r)*3072 + 2048 + h*64 + c*2);
  }
  __syncthreads();
  #pragma unroll
  for (int p=0;p<8;p++){
    int idx = p*256 + t;
    int d = idx >> 5, c = idx & 31;
    unsigned int a = tile[2*c][d>>1];
    unsigned int b = tile[2*c+1][d>>1];
    unsigned int lo = (d&1) ? (a>>16) : (a & 0xffffu);
    unsigned int hi = (d&1) ? (b>>16) : (b & 0xffffu);
    *(unsigned int*)(VT + (size_t)h*131072 + (size_t)d*2048 + n0 + c*2) = lo | (hi<<16);
  }
}

// ---- causal flash attention: barrier-free, global-direct K/V (L2-resident) --
// K/V per head = 256 KB, L2-fits (head-local XCD mapping). No LDS staging, no
// __syncthreads in the loop; per-wave Plds/fbuf/lbuf only. T13 defer-max.
__global__ __launch_bounds__(256) void flash_attn(
    const unsigned short* __restrict__ qkv,
    const unsigned short* __restrict__ VT,
    unsigned short* __restrict__ O)
{
  __shared__ unsigned short Plds[4][16*72];
  __shared__ float fbuf[4][16];
  __shared__ float lbuf[4][16];

  int t = threadIdx.x;
  int lane = t & 63;
  int w = t >> 6;
  int q15 = lane & 15, l16 = lane >> 4;

  // XCD-local heads (2 per XCD) + balanced causal pairing
  int bid = blockIdx.x;
  int x = bid & 7, r = bid >> 3;
  int h = 2*x + (r & 1);
  int q = r >> 1;
  int qt = (q < 16) ? q : 47 - q;
  int q0 = qt * 64;

  bf16x8 qF[2];
  int qrow = q0 + w*16 + q15;
  #pragma unroll
  for (int db=0; db<2; db++)
    qF[db] = *(const bf16x8*)(qkv + (size_t)qrow*3072 + h*64 + db*32 + l16*8);

  const unsigned short* Kb = qkv + 1024 + h*64;
  const unsigned short* Vb = VT + (size_t)h*131072;

  f32x4 o[4] = {};
  float m_run = -1e30f, l_run = 0.f;

  for (int kt = 0; kt <= qt; ++kt){
    int k0 = kt*64;

    // QK^T (swapped): S^T[k][q], k = km*16 + l16*4 + j, q = q15
    f32x4 s[4] = {};
    #pragma unroll
    for (int km=0;km<4;km++){
      #pragma unroll
      for (int db=0;db<2;db++){
        bf16x8 kF = *(const bf16x8*)(Kb + (size_t)(k0 + km*16 + q15)*3072 + db*32 + l16*8);
        s[km] = __builtin_amdgcn_mfma_f32_16x16x32_bf16(kF, qF[db], s[km], 0,0,0);
      }
    }

    bool diag = (kt == qt);
    float pmax = -1e30f;
    #pragma unroll
    for (int km=0;km<4;km++){
      #pragma unroll
      for (int j=0;j<4;j++){
        float sv = s[km][j] * ATT_SCALE;
        if (diag){
          int kg = km*16 + l16*4 + j;
          int qg = w*16 + q15;
          if (kg > qg) sv = -1e30f;
        }
        s[km][j] = sv;
        pmax = fmaxf(pmax, sv);
      }
    }
    pmax = fmaxf(pmax, __shfl_xor(pmax, 16));
    pmax = fmaxf(pmax, __shfl_xor(pmax, 32));

    // defer-max (T13): only rescale when the running max grew by > 8
    if (!__all(pmax - m_run <= 8.f)){
      float m_new = fmaxf(m_run, pmax);
      float f = __expf(m_run - m_new);
      m_run = m_new;
      l_run *= f;
      if (l16 == 0) fbuf[w][q15] = f;
      f32x4 fv = *(f32x4*)&fbuf[w][l16*4];
      #pragma unroll
      for (int n=0;n<4;n++) o[n] *= fv;
    }

    // P = exp(S - m_run) -> bf16 -> per-wave Plds
    float lsum = 0.f;
    #pragma unroll
    for (int km=0;km<4;km++){
      float p0 = __expf(s[km][0]-m_run);
      float p1 = __expf(s[km][1]-m_run);
      float p2 = __expf(s[km][2]-m_run);
      float p3 = __expf(s[km][3]-m_run);
      lsum += (p0+p1)+(p2+p3);
      unsigned int v0 = (unsigned int)f2bf(p0) | ((unsigned int)f2bf(p1)<<16);
      unsigned int v1 = (unsigned int)f2bf(p2) | ((unsigned int)f2bf(p3)<<16);
      *(uint2*)&Plds[w][q15*72 + km*16 + l16*4] = make_uint2(v0,v1);
    }
    lsum += __shfl_xor(lsum,16);
    lsum += __shfl_xor(lsum,32);
    l_run += lsum;

    // PV: O[q][d] += P[q][k] * V[k][d], V fragments direct from global VT
    #pragma unroll
    for (int kb=0;kb<2;kb++){
      bf16x8 aP = *(const bf16x8*)&Plds[w][q15*72 + kb*32 + l16*8];
      #pragma unroll
      for (int n=0;n<4;n++){
        bf16x8 vF = *(const bf16x8*)(Vb + (size_t)(n*16 + q15)*2048 + k0 + kb*32 + l16*8);
        o[n] = __builtin_amdgcn_mfma_f32_16x16x32_bf16(aP, vF, o[n], 0,0,0);
      }
    }
  }

  if (l16 == 0) lbuf[w][q15] = 1.f / l_run;
  f32x4 lv = *(f32x4*)&lbuf[w][l16*4];

  #pragma unroll
  for (int n=0;n<4;n++){
    #pragma unroll
    for (int j=0;j<4;j++){
      int row = q0 + w*16 + l16*4 + j;
      int col = h*64 + n*16 + q15;
      O[(size_t)row*1024 + col] = f2bf(o[n][j]*lv[j]);
    }
  }
}

extern "C" void kernel_launch(void* const* d_in, const int* in_sizes, int n_in,
                              void* d_out, int out_size, void* d_ws, size_t ws_size,
                              hipStream_t stream)
{
  (void)in_sizes; (void)n_in; (void)out_size; (void)ws_size;
  const float* x_in = (const float*)d_in[0];
  const float* Wqkv = (const float*)d_in[2];
  const float* Wo   = (const float*)d_in[3];
  const float* bo   = (const float*)d_in[4];
  const float* ln1g = (const float*)d_in[5];
  const float* ln1b = (const float*)d_in[6];
  const float* ln2g = (const float*)d_in[7];
  const float* ln2b = (const float*)d_in[8];
  const float* ls1  = (const float*)d_in[9];
  const float* ls2  = (const float*)d_in[10];
  const float* W1   = (const float*)d_in[11];
  const float* b1   = (const float*)d_in[12];
  const float* W2   = (const float*)d_in[13];
  const float* b2   = (const float*)d_in[14];
  float* X = (float*)d_out;

  char* ws = (char*)d_ws;
  unsigned short* WTq = (unsigned short*)(ws);                 // 24 MiB (4 x 3072x1024)
  unsigned short* WTo = (unsigned short*)(ws + (24u<<20));     // 8 MiB  (4 x 1024x1024)
  unsigned short* WT1 = (unsigned short*)(ws + (32u<<20));     // 64 MiB (4 x 8192x1024)
  unsigned short* WT2 = (unsigned short*)(ws + (96u<<20));     // 32 MiB (4 x 1024x4096)
  unsigned short* hb  = (unsigned short*)(ws + (128u<<20));    // 4 MiB
  unsigned short* qu  = (unsigned short*)(ws + (132u<<20));    // 12 MiB (qkv)
  unsigned short* VTg = (unsigned short*)(ws + (144u<<20));    // 4 MiB
  unsigned short* of  = (unsigned short*)(ws + (148u<<20));    // 16 MiB (o / F)
  unsigned short* PTb = (unsigned short*)(ws + (164u<<20));    // 32 MiB (bf16 SK partials)

  hipMemcpyAsync(d_out, (const void*)x_in, (size_t)2048*1024*4,
                 hipMemcpyDeviceToDevice, stream);

  // ---- all weight transposes, batched across layers ----
  trc_kernel<<<dim3(3072/64,1024/64,4),256,0,stream>>>(Wqkv, WTq, 1024, 3072);
  trc_kernel<<<dim3(1024/64,1024/64,4),256,0,stream>>>(Wo,   WTo, 1024, 1024);
  trc_w1_kernel<<<dim3(8192/64,1024/64,4),256,0,stream>>>(W1, WT1);
  trc_kernel<<<dim3(1024/64,4096/64,4),256,0,stream>>>(W2,   WT2, 4096, 1024);

  for (int l = 0; l < 4; ++l){
    // ---- attention sublayer ----
    if (l == 0)
      ln_kernel<<<2048,256,0,stream>>>(X, ln1g, ln1b, hb);
    gemm_bt<0,0><<<dim3(3072/128,2048/128),256,0,stream>>>(hb, WTq + (size_t)l*3072*1024,
        2048,3072,1024, qu, nullptr);
    vtr_kernel<<<dim3(32,16),256,0,stream>>>(qu, VTg);
    flash_attn<<<512,256,0,stream>>>(qu, VTg, of);
    gemm_bt<3,1><<<dim3(1024/128,2048/128,2),256,0,stream>>>(of, WTo + (size_t)l*1024*1024,
        2048,1024,1024, PTb, nullptr);
    redln_kernel<2,1><<<2048,256,0,stream>>>(PTb, X, bo + l*1024, ls1 + l*1024,
        ln2g + l*1024, ln2b + l*1024, hb);
    // ---- feedforward sublayer ----
    gemm_bt<4,0><<<dim3(8192/128,2048/128),256,0,stream>>>(hb, WT1 + (size_t)l*8192*1024,
        2048,8192,1024, of, b1 + (size_t)l*8192);
    gemm_bt<3,1><<<dim3(1024/128,2048/128,4),256,0,stream>>>(of, WT2 + (size_t)l*1024*4096,
        2048,1024,4096, PTb, nullptr);
    if (l < 3)
      redln_kernel<4,1><<<2048,256,0,stream>>>(PTb, X, b2 + l*1024, ls2 + l*1024,
          ln1g + (l+1)*1024, ln1b + (l+1)*1024, hb);
    else
      redln_kernel<4,0><<<2048,256,0,stream>>>(PTb, X, b2 + l*1024, ls2 + l*1024,
          nullptr, nullptr, nullptr);
  }
}

// Round 15
// 790.687 us; speedup vs baseline: 1.1440x; 1.1440x over previous
//
#include <hip/hip_runtime.h>
#include <hip/hip_bf16.h>
#include <math.h>

#define LN_EPS 1e-5f
#define ATT_SCALE 0.125f   // 64^-0.5

typedef __bf16 bf16x8 __attribute__((ext_vector_type(8)));
typedef float f32x4 __attribute__((ext_vector_type(4)));

__device__ __forceinline__ unsigned short f2bf(float f){
  unsigned int u = __builtin_bit_cast(unsigned int, f);
  u += 0x7fffu + ((u >> 16) & 1u);
  return (unsigned short)(u >> 16);
}
__device__ __forceinline__ float bfbits2f(unsigned int lo16){
  return __builtin_bit_cast(float, lo16 << 16);
}

// ---------------- LayerNorm: fp32 in -> bf16 out (row = 1024) ----------------
__global__ __launch_bounds__(256) void ln_kernel(
    const float* __restrict__ X, const float* __restrict__ g,
    const float* __restrict__ b, unsigned short* __restrict__ H)
{
  __shared__ float red[4];
  int row = blockIdx.x, t = threadIdx.x;
  const float4 xv = ((const float4*)(X + (size_t)row*1024))[t];
  float s = xv.x + xv.y + xv.z + xv.w;
  #pragma unroll
  for (int o=32;o;o>>=1) s += __shfl_down(s,o);
  if ((t&63)==0) red[t>>6] = s;
  __syncthreads();
  float mu = (red[0]+red[1]+red[2]+red[3]) * (1.f/1024.f);
  __syncthreads();
  float dx = xv.x-mu, dy = xv.y-mu, dz = xv.z-mu, dw = xv.w-mu;
  float s2 = dx*dx+dy*dy+dz*dz+dw*dw;
  #pragma unroll
  for (int o=32;o;o>>=1) s2 += __shfl_down(s2,o);
  if ((t&63)==0) red[t>>6] = s2;
  __syncthreads();
  float var = (red[0]+red[1]+red[2]+red[3]) * (1.f/1024.f);
  float rs = rsqrtf(var + LN_EPS);
  const float4 gv = ((const float4*)g)[t];
  const float4 bv = ((const float4*)b)[t];
  ushort4 o4;
  o4.x = f2bf(dx*rs*gv.x + bv.x);
  o4.y = f2bf(dy*rs*gv.y + bv.y);
  o4.z = f2bf(dz*rs*gv.z + bv.z);
  o4.w = f2bf(dw*rs*gv.w + bv.w);
  ((ushort4*)(H + (size_t)row*1024))[t] = o4;
}

// -- split-K reduce (bf16 partials, +bias,scale,residual) + optional fused LN -
template<int SK, int DO_LN>
__global__ __launch_bounds__(256) void redln_kernel(
    const unsigned short* __restrict__ P, float* __restrict__ X,
    const float* __restrict__ bias, const float* __restrict__ scale,
    const float* __restrict__ g, const float* __restrict__ b,
    unsigned short* __restrict__ H)
{
  __shared__ float red[4];
  int row = blockIdx.x, t = threadIdx.x;
  size_t off = (size_t)row*1024 + t*4;
  float4 xv = *(const float4*)(X + off);
  float4 pv;
  {
    uint2 u = *(const uint2*)(P + off);
    pv.x = bfbits2f(u.x & 0xffffu); pv.y = bfbits2f(u.x >> 16);
    pv.z = bfbits2f(u.y & 0xffffu); pv.w = bfbits2f(u.y >> 16);
  }
  #pragma unroll
  for (int c=1;c<SK;c++){
    uint2 u = *(const uint2*)(P + (size_t)c*2048*1024 + off);
    pv.x += bfbits2f(u.x & 0xffffu); pv.y += bfbits2f(u.x >> 16);
    pv.z += bfbits2f(u.y & 0xffffu); pv.w += bfbits2f(u.y >> 16);
  }
  const float4 bv = ((const float4*)bias)[t];
  const float4 sv = ((const float4*)scale)[t];
  xv.x += (pv.x+bv.x)*sv.x;
  xv.y += (pv.y+bv.y)*sv.y;
  xv.z += (pv.z+bv.z)*sv.z;
  xv.w += (pv.w+bv.w)*sv.w;
  *(float4*)(X + off) = xv;
  if (DO_LN){
    float s = xv.x + xv.y + xv.z + xv.w;
    #pragma unroll
    for (int o=32;o;o>>=1) s += __shfl_down(s,o);
    if ((t&63)==0) red[t>>6] = s;
    __syncthreads();
    float mu = (red[0]+red[1]+red[2]+red[3]) * (1.f/1024.f);
    __syncthreads();
    float dx = xv.x-mu, dy = xv.y-mu, dz = xv.z-mu, dw = xv.w-mu;
    float s2 = dx*dx+dy*dy+dz*dz+dw*dw;
    #pragma unroll
    for (int o=32;o;o>>=1) s2 += __shfl_down(s2,o);
    if ((t&63)==0) red[t>>6] = s2;
    __syncthreads();
    float var = (red[0]+red[1]+red[2]+red[3]) * (1.f/1024.f);
    float rs = rsqrtf(var + LN_EPS);
    const float4 gv = ((const float4*)g)[t];
    const float4 lbv = ((const float4*)b)[t];
    ushort4 o4;
    o4.x = f2bf(dx*rs*gv.x + lbv.x);
    o4.y = f2bf(dy*rs*gv.y + lbv.y);
    o4.z = f2bf(dz*rs*gv.z + lbv.z);
    o4.w = f2bf(dw*rs*gv.w + lbv.w);
    ((ushort4*)(H + (size_t)row*1024))[t] = o4;
  }
}

// -- transpose + fp32->bf16 convert, all layers batched: W (L,KxN) -> WT (L,NxK)
__global__ __launch_bounds__(256) void trc_kernel(
    const float* __restrict__ W, unsigned short* __restrict__ WT, int K, int N)
{
  __shared__ float tile[64][65];
  const float* Wz = W + (size_t)blockIdx.z*K*N;
  unsigned short* WTz = WT + (size_t)blockIdx.z*K*N;
  int n0 = blockIdx.x*64, k0 = blockIdx.y*64;
  int t = threadIdx.x;
  int tx = t & 63, ty = t >> 6;
  #pragma unroll
  for (int p=0;p<16;p++){
    int r = ty*16+p;
    tile[r][tx] = Wz[(size_t)(k0+r)*N + n0 + tx];
  }
  __syncthreads();
  int kc = t & 31, tb = t >> 5;
  #pragma unroll
  for (int p=0;p<8;p++){
    int nr = tb + p*8;
    unsigned int lo = f2bf(tile[2*kc][nr]);
    unsigned int hi = f2bf(tile[2*kc+1][nr]);
    ((unsigned int*)(WTz + (size_t)(n0+nr)*K + k0))[kc] = lo | (hi<<16);
  }
}

// --- W1 transpose, a/g 16-col interleave, batched: W1 (L,1024x8192) -> WT ----
__global__ __launch_bounds__(256) void trc_w1_kernel(
    const float* __restrict__ W, unsigned short* __restrict__ WT)
{
  __shared__ float tile[64][65];
  const float* Wz = W + (size_t)blockIdx.z*1024*8192;
  unsigned short* WTz = WT + (size_t)blockIdx.z*1024*8192;
  int n0 = blockIdx.x*64, k0 = blockIdx.y*64;
  int ca = (n0>>5)*16;
  int t = threadIdx.x;
  int tx = t & 63, ty = t >> 6;
  #pragma unroll
  for (int p=0;p<16;p++){
    int r = ty*16+p;
    int col = (tx < 32) ? (ca + tx) : (ca + 4064 + tx);
    tile[r][tx] = Wz[(size_t)(k0+r)*8192 + col];
  }
  __syncthreads();
  int kc = t & 31, tb = t >> 5;
  #pragma unroll
  for (int p=0;p<8;p++){
    int nr = tb + p*8;
    int rr = nr & 31;
    int vcol = (nr>>5)*16 + (rr&15) + ((rr>>4)<<5);
    unsigned int lo = f2bf(tile[2*kc][vcol]);
    unsigned int hi = f2bf(tile[2*kc+1][vcol]);
    ((unsigned int*)(WTz + (size_t)(n0+nr)*1024 + k0))[kc] = lo | (hi<<16);
  }
}

// ----------- bf16 MFMA GEMM, 128x128, BK=64, 2-phase double-buffer -----------
// MODE 0: Obf = A@B (bf16, ld N)
// MODE 3: split-K bf16 partials at Obf[z*M*N + ...]
// MODE 4: GEGLU epilogue (WT a/g-interleaved): Obf = a*gelu(g), ld 4096
// All epilogues LDS-bounced for coalesced uint4 stores.
template<int MODE, int SWZ>
__global__ __launch_bounds__(256) void gemm_bt(
    const unsigned short* __restrict__ A, const unsigned short* __restrict__ BT,
    int M, int N, int K,
    unsigned short* __restrict__ Obf,
    const float* __restrict__ bias)
{
  __shared__ unsigned short Asm[2][128*64];
  __shared__ unsigned short Bsm[2][128*64];
  int t = threadIdx.x;
  int lane = t & 63;
  int w = t >> 6, wm = w >> 1, wn = w & 1;

  int bn, bm;
  if (SWZ){
    int nwg = gridDim.x * gridDim.y;
    int wg = blockIdx.y * gridDim.x + blockIdx.x;
    int cpx = nwg >> 3;
    int swz = (wg & 7) * cpx + (wg >> 3);
    bn = swz % gridDim.x; bm = swz / gridDim.x;
  } else {
    bn = blockIdx.x; bm = blockIdx.y;
  }

  f32x4 acc[4][4] = {};
  int ktBeg = 0, ktEnd = K >> 6;
  if (MODE == 3){
    int per = (K >> 6) / gridDim.z;
    ktBeg = blockIdx.z * per;
    ktEnd = ktBeg + per;
  }

  int srow = t >> 3, ssc = t & 7;
  auto STAGE = [&](int kt, int buf){
    #pragma unroll
    for (int c=0;c<4;c++){
      int row = c*32 + srow;
      int gc = ssc ^ (row & 7);
      const unsigned short* sa = A  + (size_t)(bm*128 + row)*K + kt*64 + gc*8;
      const unsigned short* sb = BT + (size_t)(bn*128 + row)*K + kt*64 + gc*8;
      __builtin_amdgcn_global_load_lds(
        (const __attribute__((address_space(1))) unsigned int*)sa,
        (__attribute__((address_space(3))) unsigned int*)(&Asm[buf][(c*256 + (t & ~63))*8]),
        16, 0, 0);
      __builtin_amdgcn_global_load_lds(
        (const __attribute__((address_space(1))) unsigned int*)sb,
        (__attribute__((address_space(3))) unsigned int*)(&Bsm[buf][(c*256 + (t & ~63))*8]),
        16, 0, 0);
    }
  };

  STAGE(ktBeg, 0);
  __syncthreads();
  int cur = 0;
  for (int kt = ktBeg; kt < ktEnd; ++kt){
    if (kt + 1 < ktEnd) STAGE(kt + 1, cur ^ 1);
    #pragma unroll
    for (int kk=0;kk<2;kk++){
      bf16x8 aF[4], bF[4];
      #pragma unroll
      for (int m=0;m<4;m++){
        int row = wm*64 + m*16 + (lane&15);
        int ch = kk*4 + (lane>>4);
        aF[m] = *(const bf16x8*)&Asm[cur][row*64 + (ch ^ (row&7))*8];
      }
      #pragma unroll
      for (int n=0;n<4;n++){
        int row = wn*64 + n*16 + (lane&15);
        int ch = kk*4 + (lane>>4);
        bF[n] = *(const bf16x8*)&Bsm[cur][row*64 + (ch ^ (row&7))*8];
      }
      __builtin_amdgcn_s_setprio(1);
      #pragma unroll
      for (int m=0;m<4;m++)
        #pragma unroll
        for (int n=0;n<4;n++)
          acc[m][n] = __builtin_amdgcn_mfma_f32_16x16x32_bf16(aF[m], bF[n], acc[m][n], 0,0,0);
      __builtin_amdgcn_s_setprio(0);
    }
    __syncthreads();                 // includes vmcnt(0) drain: Asm/Bsm dead after
    cur ^= 1;
  }

  // ---- coalesced epilogue via LDS bounce (reuse Asm: 16384 shorts) ----
  unsigned short* ep = &Asm[0][0];
  int colg = lane & 15;
  int r0 = wm*64 + (lane>>4)*4;      // +m*16 +j
  if (MODE==4){
    float b1a[2], b1g[2];
    #pragma unroll
    for (int p=0;p<2;p++){
      int oc = (bn*4 + wn*2 + p)*16 + colg;
      b1a[p] = bias[oc];
      b1g[p] = bias[oc + 4096];
    }
    #pragma unroll
    for (int m=0;m<4;m++){
      #pragma unroll
      for (int p=0;p<2;p++){
        int cw = (wn*2 + p)*16 + colg;              // 0..63
        #pragma unroll
        for (int j=0;j<4;j++){
          float va = acc[m][2*p][j]   + b1a[p];
          float vg = acc[m][2*p+1][j] + b1g[p];
          float f = va * (0.5f * vg * (1.f + erff(vg * 0.70710678118f)));
          ep[(r0 + m*16 + j)*64 + cw] = f2bf(f);
        }
      }
    }
    __syncthreads();
    #pragma unroll
    for (int i=0;i<4;i++){
      int idx = i*256 + t;
      int row = idx >> 3, ch = idx & 7;
      *(uint4*)&Obf[(size_t)(bm*128+row)*4096 + bn*64 + ch*8] = *(const uint4*)&ep[row*64 + ch*8];
    }
    return;
  }
  #pragma unroll
  for (int m=0;m<4;m++)
    #pragma unroll
    for (int n=0;n<4;n++){
      int cw = wn*64 + n*16 + colg;                 // 0..127
      #pragma unroll
      for (int j=0;j<4;j++)
        ep[(r0 + m*16 + j)*128 + cw] = f2bf(acc[m][n][j]);
    }
  __syncthreads();
  size_t zoff = (MODE==3) ? (size_t)blockIdx.z*((size_t)M*N) : 0;
  #pragma unroll
  for (int i=0;i<8;i++){
    int idx = i*256 + t;
    int row = idx >> 4, ch = idx & 15;
    *(uint4*)&Obf[zoff + (size_t)(bm*128+row)*N + bn*128 + ch*8] = *(const uint4*)&ep[row*128 + ch*8];
  }
}

// ------------- V transpose: qkv (2048x3072) -> VT [16][64][2048] -------------
__global__ __launch_bounds__(256) void vtr_kernel(
    const unsigned short* __restrict__ qkv, unsigned short* __restrict__ VT)
{
  __shared__ unsigned int tile[64][33];
  int h = blockIdx.y;
  int n0 = blockIdx.x * 64;
  int t = threadIdx.x;
  #pragma unroll
  for (int p=0;p<8;p++){
    int idx = p*256 + t;
    int r = idx >> 5, c = idx & 31;
    tile[r][c] = *(const unsigned int*)(qkv + (size_t)(n0+r)*3072 + 2048 + h*64 + c*2);
  }
  __syncthreads();
  #pragma unroll
  for (int p=0;p<8;p++){
    int idx = p*256 + t;
    int d = idx >> 5, c = idx & 31;
    unsigned int a = tile[2*c][d>>1];
    unsigned int b = tile[2*c+1][d>>1];
    unsigned int lo = (d&1) ? (a>>16) : (a & 0xffffu);
    unsigned int hi = (d&1) ? (b>>16) : (b & 0xffffu);
    *(unsigned int*)(VT + (size_t)h*131072 + (size_t)d*2048 + n0 + c*2) = lo | (hi<<16);
  }
}

// ------- causal flash attention, MFMA, 64-q-row blocks, 2-phase dbuf ---------
// staged K/V in LDS (R13 structure) + T13 defer-max (threshold 8)
__global__ __launch_bounds__(256) void flash_attn(
    const unsigned short* __restrict__ qkv,
    const unsigned short* __restrict__ VT,
    unsigned short* __restrict__ O)
{
  __shared__ unsigned short Klds[2][64*64];
  __shared__ unsigned short Vlds[2][64*64];
  __shared__ unsigned short Plds[4][16*72];
  __shared__ float fbuf[4][16];
  __shared__ float lbuf[4][16];

  int t = threadIdx.x;
  int lane = t & 63;
  int w = t >> 6;
  int q15 = lane & 15, l16 = lane >> 4;

  int bid = blockIdx.x;
  int x = bid & 7, r = bid >> 3;
  int h = 2*x + (r & 1);
  int q = r >> 1;
  int qt = (q < 16) ? q : 47 - q;
  int q0 = qt * 64;

  bf16x8 qF[2];
  int qrow = q0 + w*16 + q15;
  #pragma unroll
  for (int db=0; db<2; db++)
    qF[db] = *(const bf16x8*)(qkv + (size_t)qrow*3072 + h*64 + db*32 + l16*8);

  int srow = t >> 3, ssc = t & 7;
  auto STAGE = [&](int kt, int buf){
    int k0 = kt*64;
    #pragma unroll
    for (int c=0;c<2;c++){
      int row = c*32 + srow;
      int gc = ssc ^ (row & 7);
      const unsigned short* sk = qkv + (size_t)(k0+row)*3072 + 1024 + h*64 + gc*8;
      const unsigned short* sv = VT + (size_t)h*131072 + (size_t)row*2048 + k0 + gc*8;
      __builtin_amdgcn_global_load_lds(
        (const __attribute__((address_space(1))) unsigned int*)sk,
        (__attribute__((address_space(3))) unsigned int*)(&Klds[buf][(c*256 + (t & ~63))*8]),
        16, 0, 0);
      __builtin_amdgcn_global_load_lds(
        (const __attribute__((address_space(1))) unsigned int*)sv,
        (__attribute__((address_space(3))) unsigned int*)(&Vlds[buf][(c*256 + (t & ~63))*8]),
        16, 0, 0);
    }
  };

  f32x4 o[4] = {};
  float m_run = -1e30f, l_run = 0.f;

  STAGE(0, 0);
  __syncthreads();
  int cur = 0;
  for (int kt = 0; kt <= qt; ++kt){
    if (kt < qt) STAGE(kt + 1, cur ^ 1);

    f32x4 s[4] = {};
    #pragma unroll
    for (int km=0;km<4;km++){
      #pragma unroll
      for (int db=0;db<2;db++){
        int row = km*16 + q15;
        int ch = db*4 + l16;
        bf16x8 kF = *(const bf16x8*)&Klds[cur][row*64 + (ch ^ (row&7))*8];
        s[km] = __builtin_amdgcn_mfma_f32_16x16x32_bf16(kF, qF[db], s[km], 0,0,0);
      }
    }

    bool diag = (kt == qt);
    float pmax = -1e30f;
    #pragma unroll
    for (int km=0;km<4;km++){
      #pragma unroll
      for (int j=0;j<4;j++){
        float sv = s[km][j] * ATT_SCALE;
        if (diag){
          int kg = km*16 + l16*4 + j;
          int qg = w*16 + q15;
          if (kg > qg) sv = -1e30f;
        }
        s[km][j] = sv;
        pmax = fmaxf(pmax, sv);
      }
    }
    pmax = fmaxf(pmax, __shfl_xor(pmax, 16));
    pmax = fmaxf(pmax, __shfl_xor(pmax, 32));

    // T13 defer-max: rescale only when running max grows by > 8
    if (!__all(pmax - m_run <= 8.f)){
      float m_new = fmaxf(m_run, pmax);
      float f = __expf(m_run - m_new);
      m_run = m_new;
      l_run *= f;
      if (l16 == 0) fbuf[w][q15] = f;
      f32x4 fv = *(f32x4*)&fbuf[w][l16*4];
      #pragma unroll
      for (int n=0;n<4;n++) o[n] *= fv;
    }

    float lsum = 0.f;
    #pragma unroll
    for (int km=0;km<4;km++){
      float p0 = __expf(s[km][0]-m_run);
      float p1 = __expf(s[km][1]-m_run);
      float p2 = __expf(s[km][2]-m_run);
      float p3 = __expf(s[km][3]-m_run);
      lsum += (p0+p1)+(p2+p3);
      unsigned int v0 = (unsigned int)f2bf(p0) | ((unsigned int)f2bf(p1)<<16);
      unsigned int v1 = (unsigned int)f2bf(p2) | ((unsigned int)f2bf(p3)<<16);
      *(uint2*)&Plds[w][q15*72 + km*16 + l16*4] = make_uint2(v0,v1);
    }
    lsum += __shfl_xor(lsum,16);
    lsum += __shfl_xor(lsum,32);
    l_run += lsum;

    #pragma unroll
    for (int kb=0;kb<2;kb++){
      bf16x8 aP = *(const bf16x8*)&Plds[w][q15*72 + kb*32 + l16*8];
      #pragma unroll
      for (int n=0;n<4;n++){
        int row = n*16 + q15;
        int ch = kb*4 + l16;
        bf16x8 vF = *(const bf16x8*)&Vlds[cur][row*64 + (ch ^ (row&7))*8];
        o[n] = __builtin_amdgcn_mfma_f32_16x16x32_bf16(aP, vF, o[n], 0,0,0);
      }
    }
    __syncthreads();
    cur ^= 1;
  }

  if (l16 == 0) lbuf[w][q15] = 1.f / l_run;
  f32x4 lv = *(f32x4*)&lbuf[w][l16*4];

  #pragma unroll
  for (int n=0;n<4;n++){
    #pragma unroll
    for (int j=0;j<4;j++){
      int row = q0 + w*16 + l16*4 + j;
      int col = h*64 + n*16 + q15;
      O[(size_t)row*1024 + col] = f2bf(o[n][j]*lv[j]);
    }
  }
}

extern "C" void kernel_launch(void* const* d_in, const int* in_sizes, int n_in,
                              void* d_out, int out_size, void* d_ws, size_t ws_size,
                              hipStream_t stream)
{
  (void)in_sizes; (void)n_in; (void)out_size; (void)ws_size;
  const float* x_in = (const float*)d_in[0];
  const float* Wqkv = (const float*)d_in[2];
  const float* Wo   = (const float*)d_in[3];
  const float* bo   = (const float*)d_in[4];
  const float* ln1g = (const float*)d_in[5];
  const float* ln1b = (const float*)d_in[6];
  const float* ln2g = (const float*)d_in[7];
  const float* ln2b = (const float*)d_in[8];
  const float* ls1  = (const float*)d_in[9];
  const float* ls2  = (const float*)d_in[10];
  const float* W1   = (const float*)d_in[11];
  const float* b1   = (const float*)d_in[12];
  const float* W2   = (const float*)d_in[13];
  const float* b2   = (const float*)d_in[14];
  float* X = (float*)d_out;

  char* ws = (char*)d_ws;
  unsigned short* WTq = (unsigned short*)(ws);                 // 24 MiB (4 x 3072x1024)
  unsigned short* WTo = (unsigned short*)(ws + (24u<<20));     // 8 MiB  (4 x 1024x1024)
  unsigned short* WT1 = (unsigned short*)(ws + (32u<<20));     // 64 MiB (4 x 8192x1024)
  unsigned short* WT2 = (unsigned short*)(ws + (96u<<20));     // 32 MiB (4 x 1024x4096)
  unsigned short* hb  = (unsigned short*)(ws + (128u<<20));    // 4 MiB
  unsigned short* qu  = (unsigned short*)(ws + (132u<<20));    // 12 MiB (qkv)
  unsigned short* VTg = (unsigned short*)(ws + (144u<<20));    // 4 MiB
  unsigned short* of  = (unsigned short*)(ws + (148u<<20));    // 16 MiB (o / F)
  unsigned short* PTb = (unsigned short*)(ws + (164u<<20));    // 32 MiB (bf16 SK partials)

  hipMemcpyAsync(d_out, (const void*)x_in, (size_t)2048*1024*4,
                 hipMemcpyDeviceToDevice, stream);

  // ---- all weight transposes, batched across layers ----
  trc_kernel<<<dim3(3072/64,1024/64,4),256,0,stream>>>(Wqkv, WTq, 1024, 3072);
  trc_kernel<<<dim3(1024/64,1024/64,4),256,0,stream>>>(Wo,   WTo, 1024, 1024);
  trc_w1_kernel<<<dim3(8192/64,1024/64,4),256,0,stream>>>(W1, WT1);
  trc_kernel<<<dim3(1024/64,4096/64,4),256,0,stream>>>(W2,   WT2, 4096, 1024);

  for (int l = 0; l < 4; ++l){
    // ---- attention sublayer ----
    if (l == 0)
      ln_kernel<<<2048,256,0,stream>>>(X, ln1g, ln1b, hb);
    gemm_bt<0,0><<<dim3(3072/128,2048/128),256,0,stream>>>(hb, WTq + (size_t)l*3072*1024,
        2048,3072,1024, qu, nullptr);
    vtr_kernel<<<dim3(32,16),256,0,stream>>>(qu, VTg);
    flash_attn<<<512,256,0,stream>>>(qu, VTg, of);
    gemm_bt<3,1><<<dim3(1024/128,2048/128,2),256,0,stream>>>(of, WTo + (size_t)l*1024*1024,
        2048,1024,1024, PTb, nullptr);
    redln_kernel<2,1><<<2048,256,0,stream>>>(PTb, X, bo + l*1024, ls1 + l*1024,
        ln2g + l*1024, ln2b + l*1024, hb);
    // ---- feedforward sublayer ----
    gemm_bt<4,0><<<dim3(8192/128,2048/128),256,0,stream>>>(hb, WT1 + (size_t)l*8192*1024,
        2048,8192,1024, of, b1 + (size_t)l*8192);
    gemm_bt<3,1><<<dim3(1024/128,2048/128,4),256,0,stream>>>(of, WT2 + (size_t)l*1024*4096,
        2048,1024,4096, PTb, nullptr);
    if (l < 3)
      redln_kernel<4,1><<<2048,256,0,stream>>>(PTb, X, b2 + l*1024, ls2 + l*1024,
          ln1g + (l+1)*1024, ln1b + (l+1)*1024, hb);
    else
      redln_kernel<4,0><<<2048,256,0,stream>>>(PTb, X, b2 + l*1024, ls2 + l*1024,
          nullptr, nullptr, nullptr);
  }
}

// Round 16
// 742.571 us; speedup vs baseline: 1.2182x; 1.0648x over previous
//
#include <hip/hip_runtime.h>
#include <hip/hip_bf16.h>
#include <math.h>

#define LN_EPS 1e-5f
#define ATT_SCALE 0.125f   // 64^-0.5

typedef __bf16 bf16x8 __attribute__((ext_vector_type(8)));
typedef float f32x4 __attribute__((ext_vector_type(4)));

__device__ __forceinline__ unsigned short f2bf(float f){
  unsigned int u = __builtin_bit_cast(unsigned int, f);
  u += 0x7fffu + ((u >> 16) & 1u);
  return (unsigned short)(u >> 16);
}
__device__ __forceinline__ float bfbits2f(unsigned int lo16){
  return __builtin_bit_cast(float, lo16 << 16);
}

// ---------------- LayerNorm: fp32 in -> bf16 out (row = 1024) ----------------
__global__ __launch_bounds__(256) void ln_kernel(
    const float* __restrict__ X, const float* __restrict__ g,
    const float* __restrict__ b, unsigned short* __restrict__ H)
{
  __shared__ float red[4];
  int row = blockIdx.x, t = threadIdx.x;
  const float4 xv = ((const float4*)(X + (size_t)row*1024))[t];
  float s = xv.x + xv.y + xv.z + xv.w;
  #pragma unroll
  for (int o=32;o;o>>=1) s += __shfl_down(s,o);
  if ((t&63)==0) red[t>>6] = s;
  __syncthreads();
  float mu = (red[0]+red[1]+red[2]+red[3]) * (1.f/1024.f);
  __syncthreads();
  float dx = xv.x-mu, dy = xv.y-mu, dz = xv.z-mu, dw = xv.w-mu;
  float s2 = dx*dx+dy*dy+dz*dz+dw*dw;
  #pragma unroll
  for (int o=32;o;o>>=1) s2 += __shfl_down(s2,o);
  if ((t&63)==0) red[t>>6] = s2;
  __syncthreads();
  float var = (red[0]+red[1]+red[2]+red[3]) * (1.f/1024.f);
  float rs = rsqrtf(var + LN_EPS);
  const float4 gv = ((const float4*)g)[t];
  const float4 bv = ((const float4*)b)[t];
  ushort4 o4;
  o4.x = f2bf(dx*rs*gv.x + bv.x);
  o4.y = f2bf(dy*rs*gv.y + bv.y);
  o4.z = f2bf(dz*rs*gv.z + bv.z);
  o4.w = f2bf(dw*rs*gv.w + bv.w);
  ((ushort4*)(H + (size_t)row*1024))[t] = o4;
}

// -- split-K reduce (bf16 partials, +bias,scale,residual) + optional fused LN -
template<int SK, int DO_LN>
__global__ __launch_bounds__(256) void redln_kernel(
    const unsigned short* __restrict__ P, float* __restrict__ X,
    const float* __restrict__ bias, const float* __restrict__ scale,
    const float* __restrict__ g, const float* __restrict__ b,
    unsigned short* __restrict__ H)
{
  __shared__ float red[4];
  int row = blockIdx.x, t = threadIdx.x;
  size_t off = (size_t)row*1024 + t*4;
  float4 xv = *(const float4*)(X + off);
  float4 pv;
  {
    uint2 u = *(const uint2*)(P + off);
    pv.x = bfbits2f(u.x & 0xffffu); pv.y = bfbits2f(u.x >> 16);
    pv.z = bfbits2f(u.y & 0xffffu); pv.w = bfbits2f(u.y >> 16);
  }
  #pragma unroll
  for (int c=1;c<SK;c++){
    uint2 u = *(const uint2*)(P + (size_t)c*2048*1024 + off);
    pv.x += bfbits2f(u.x & 0xffffu); pv.y += bfbits2f(u.x >> 16);
    pv.z += bfbits2f(u.y & 0xffffu); pv.w += bfbits2f(u.y >> 16);
  }
  const float4 bv = ((const float4*)bias)[t];
  const float4 sv = ((const float4*)scale)[t];
  xv.x += (pv.x+bv.x)*sv.x;
  xv.y += (pv.y+bv.y)*sv.y;
  xv.z += (pv.z+bv.z)*sv.z;
  xv.w += (pv.w+bv.w)*sv.w;
  *(float4*)(X + off) = xv;
  if (DO_LN){
    float s = xv.x + xv.y + xv.z + xv.w;
    #pragma unroll
    for (int o=32;o;o>>=1) s += __shfl_down(s,o);
    if ((t&63)==0) red[t>>6] = s;
    __syncthreads();
    float mu = (red[0]+red[1]+red[2]+red[3]) * (1.f/1024.f);
    __syncthreads();
    float dx = xv.x-mu, dy = xv.y-mu, dz = xv.z-mu, dw = xv.w-mu;
    float s2 = dx*dx+dy*dy+dz*dz+dw*dw;
    #pragma unroll
    for (int o=32;o;o>>=1) s2 += __shfl_down(s2,o);
    if ((t&63)==0) red[t>>6] = s2;
    __syncthreads();
    float var = (red[0]+red[1]+red[2]+red[3]) * (1.f/1024.f);
    float rs = rsqrtf(var + LN_EPS);
    const float4 gv = ((const float4*)g)[t];
    const float4 lbv = ((const float4*)b)[t];
    ushort4 o4;
    o4.x = f2bf(dx*rs*gv.x + lbv.x);
    o4.y = f2bf(dy*rs*gv.y + lbv.y);
    o4.z = f2bf(dz*rs*gv.z + lbv.z);
    o4.w = f2bf(dw*rs*gv.w + lbv.w);
    ((ushort4*)(H + (size_t)row*1024))[t] = o4;
  }
}

// -- transpose + fp32->bf16 convert, all layers batched: W (L,KxN) -> WT (L,NxK)
__global__ __launch_bounds__(256) void trc_kernel(
    const float* __restrict__ W, unsigned short* __restrict__ WT, int K, int N)
{
  __shared__ float tile[64][65];
  const float* Wz = W + (size_t)blockIdx.z*K*N;
  unsigned short* WTz = WT + (size_t)blockIdx.z*K*N;
  int n0 = blockIdx.x*64, k0 = blockIdx.y*64;
  int t = threadIdx.x;
  int tx = t & 63, ty = t >> 6;
  #pragma unroll
  for (int p=0;p<16;p++){
    int r = ty*16+p;
    tile[r][tx] = Wz[(size_t)(k0+r)*N + n0 + tx];
  }
  __syncthreads();
  int kc = t & 31, tb = t >> 5;
  #pragma unroll
  for (int p=0;p<8;p++){
    int nr = tb + p*8;
    unsigned int lo = f2bf(tile[2*kc][nr]);
    unsigned int hi = f2bf(tile[2*kc+1][nr]);
    ((unsigned int*)(WTz + (size_t)(n0+nr)*K + k0))[kc] = lo | (hi<<16);
  }
}

// --- W1 transpose, a/g 16-col interleave, batched: W1 (L,1024x8192) -> WT ----
__global__ __launch_bounds__(256) void trc_w1_kernel(
    const float* __restrict__ W, unsigned short* __restrict__ WT)
{
  __shared__ float tile[64][65];
  const float* Wz = W + (size_t)blockIdx.z*1024*8192;
  unsigned short* WTz = WT + (size_t)blockIdx.z*1024*8192;
  int n0 = blockIdx.x*64, k0 = blockIdx.y*64;
  int ca = (n0>>5)*16;
  int t = threadIdx.x;
  int tx = t & 63, ty = t >> 6;
  #pragma unroll
  for (int p=0;p<16;p++){
    int r = ty*16+p;
    int col = (tx < 32) ? (ca + tx) : (ca + 4064 + tx);
    tile[r][tx] = Wz[(size_t)(k0+r)*8192 + col];
  }
  __syncthreads();
  int kc = t & 31, tb = t >> 5;
  #pragma unroll
  for (int p=0;p<8;p++){
    int nr = tb + p*8;
    int rr = nr & 31;
    int vcol = (nr>>5)*16 + (rr&15) + ((rr>>4)<<5);
    unsigned int lo = f2bf(tile[2*kc][vcol]);
    unsigned int hi = f2bf(tile[2*kc+1][vcol]);
    ((unsigned int*)(WTz + (size_t)(n0+nr)*1024 + k0))[kc] = lo | (hi<<16);
  }
}

// ----------- bf16 MFMA GEMM, 128x128, BK=64, 2-phase double-buffer -----------
// MODE 0: Obf = A@B (bf16, ld N) ; MODE 3: split-K bf16 partials
template<int MODE, int SWZ>
__global__ __launch_bounds__(256) void gemm_bt(
    const unsigned short* __restrict__ A, const unsigned short* __restrict__ BT,
    int M, int N, int K,
    unsigned short* __restrict__ Obf,
    const float* __restrict__ bias)
{
  __shared__ unsigned short Asm[2][128*64];
  __shared__ unsigned short Bsm[2][128*64];
  int t = threadIdx.x;
  int lane = t & 63;
  int w = t >> 6, wm = w >> 1, wn = w & 1;

  int bn, bm;
  if (SWZ){
    int nwg = gridDim.x * gridDim.y;
    int wg = blockIdx.y * gridDim.x + blockIdx.x;
    int cpx = nwg >> 3;
    int swz = (wg & 7) * cpx + (wg >> 3);
    bn = swz % gridDim.x; bm = swz / gridDim.x;
  } else {
    bn = blockIdx.x; bm = blockIdx.y;
  }

  f32x4 acc[4][4] = {};
  int ktBeg = 0, ktEnd = K >> 6;
  if (MODE == 3){
    int per = (K >> 6) / gridDim.z;
    ktBeg = blockIdx.z * per;
    ktEnd = ktBeg + per;
  }

  int srow = t >> 3, ssc = t & 7;
  auto STAGE = [&](int kt, int buf){
    #pragma unroll
    for (int c=0;c<4;c++){
      int row = c*32 + srow;
      int gc = ssc ^ (row & 7);
      const unsigned short* sa = A  + (size_t)(bm*128 + row)*K + kt*64 + gc*8;
      const unsigned short* sb = BT + (size_t)(bn*128 + row)*K + kt*64 + gc*8;
      __builtin_amdgcn_global_load_lds(
        (const __attribute__((address_space(1))) unsigned int*)sa,
        (__attribute__((address_space(3))) unsigned int*)(&Asm[buf][(c*256 + (t & ~63))*8]),
        16, 0, 0);
      __builtin_amdgcn_global_load_lds(
        (const __attribute__((address_space(1))) unsigned int*)sb,
        (__attribute__((address_space(3))) unsigned int*)(&Bsm[buf][(c*256 + (t & ~63))*8]),
        16, 0, 0);
    }
  };

  STAGE(ktBeg, 0);
  __syncthreads();
  int cur = 0;
  for (int kt = ktBeg; kt < ktEnd; ++kt){
    if (kt + 1 < ktEnd) STAGE(kt + 1, cur ^ 1);
    #pragma unroll
    for (int kk=0;kk<2;kk++){
      bf16x8 aF[4], bF[4];
      #pragma unroll
      for (int m=0;m<4;m++){
        int row = wm*64 + m*16 + (lane&15);
        int ch = kk*4 + (lane>>4);
        aF[m] = *(const bf16x8*)&Asm[cur][row*64 + (ch ^ (row&7))*8];
      }
      #pragma unroll
      for (int n=0;n<4;n++){
        int row = wn*64 + n*16 + (lane&15);
        int ch = kk*4 + (lane>>4);
        bF[n] = *(const bf16x8*)&Bsm[cur][row*64 + (ch ^ (row&7))*8];
      }
      __builtin_amdgcn_s_setprio(1);
      #pragma unroll
      for (int m=0;m<4;m++)
        #pragma unroll
        for (int n=0;n<4;n++)
          acc[m][n] = __builtin_amdgcn_mfma_f32_16x16x32_bf16(aF[m], bF[n], acc[m][n], 0,0,0);
      __builtin_amdgcn_s_setprio(0);
    }
    __syncthreads();
    cur ^= 1;
  }

  // ---- coalesced epilogue via LDS bounce (reuse Asm) ----
  unsigned short* ep = &Asm[0][0];
  int colg = lane & 15;
  int r0 = wm*64 + (lane>>4)*4;
  #pragma unroll
  for (int m=0;m<4;m++)
    #pragma unroll
    for (int n=0;n<4;n++){
      int cw = wn*64 + n*16 + colg;
      #pragma unroll
      for (int j=0;j<4;j++)
        ep[(r0 + m*16 + j)*128 + cw] = f2bf(acc[m][n][j]);
    }
  __syncthreads();
  size_t zoff = (MODE==3) ? (size_t)blockIdx.z*((size_t)M*N) : 0;
  #pragma unroll
  for (int i=0;i<8;i++){
    int idx = i*256 + t;
    int row = idx >> 4, ch = idx & 15;
    *(uint4*)&Obf[zoff + (size_t)(bm*128+row)*N + bn*128 + ch*8] = *(const uint4*)&ep[row*128 + ch*8];
  }
}

// ====== W1 256x256 8-phase GEMM, derived-waits (guide template), GEGLU =======
// LDS: [2 buf][A/B][2 half(128 rows)][128][64] bf16 = 128 KiB.
// Per tile t (4 phases): stage order Ahi(t+1), Bhi(t+1), Blo(t+2), Alo(t+2);
// vmcnt(4) at each tile's trailing barrier (vmcnt(0) at t==nkt-2).
// Invariant: <=4 outstanding after each wait => all of tile t+1 complete.
#define G8F() asm volatile("" ::: "memory")
#define G8BAR() do { G8F(); __builtin_amdgcn_s_barrier(); G8F(); } while(0)
#define G8VW4() asm volatile("s_waitcnt vmcnt(4)" ::: "memory")
#define G8VW0() asm volatile("s_waitcnt vmcnt(0)" ::: "memory")

__global__ __launch_bounds__(512,2) void gemm8_w1(
    const unsigned short* __restrict__ A, const unsigned short* __restrict__ BT,
    unsigned short* __restrict__ Fout, const float* __restrict__ b1)
{
  __shared__ __attribute__((aligned(16))) unsigned short lds[65536]; // 128 KiB
  const int K = 1024, nkt = 16;
  int t = threadIdx.x;
  int lane = t & 63;
  int w = t >> 6;
  int wm = w >> 2, wn = w & 3;            // 2M x 4N waves; per-wave out 128x64
  int bh = wn >> 1;                        // which B half this wave reads
  int q15 = lane & 15, l16 = lane >> 4;
  int bn = blockIdx.x, bm = blockIdx.y;    // no swizzle: XCD = bn%8 col groups
  int rA0 = bm*256, rB0 = bn*256;

  // stage one half-tile (128 rows x 64 cols): 2 loads/thread
  auto STG = [&](const unsigned short* Mat, int r0, int kt, int half, int buf, int isB){
    int base = buf*32768 + isB*16384 + half*8192;
    #pragma unroll
    for (int l=0;l<2;l++){
      int li = l*512 + t;
      int row = li >> 3, sc = li & 7;
      int gc = sc ^ (row & 7);
      const unsigned short* src = Mat + (size_t)(r0 + half*128 + row)*K + kt*64 + gc*8;
      __builtin_amdgcn_global_load_lds(
        (const __attribute__((address_space(1))) unsigned int*)src,
        (__attribute__((address_space(3))) unsigned int*)(&lds[base + (l*512 + (t & ~63))*8]),
        16, 0, 0);
    }
  };

  f32x4 acc[8][4] = {};
  bf16x8 aF[4][2], bF0[2][2], bF1[2][2];

  auto RD_A = [&](int mh, int buf){
    int base = buf*32768 + wm*8192;
    #pragma unroll
    for (int m=0;m<4;m++){
      int r = mh*64 + m*16 + q15;
      #pragma unroll
      for (int kk=0;kk<2;kk++)
        aF[m][kk] = *(const bf16x8*)&lds[base + r*64 + (((kk*4+l16) ^ (r&7))*8)];
    }
  };
  auto RD_B = [&](bf16x8 (*dst)[2], int h, int buf){
    int base = buf*32768 + 16384 + bh*8192;
    #pragma unroll
    for (int n=0;n<2;n++){
      int r = (wn&1)*64 + (h*2+n)*16 + q15;
      #pragma unroll
      for (int kk=0;kk<2;kk++)
        dst[n][kk] = *(const bf16x8*)&lds[base + r*64 + (((kk*4+l16) ^ (r&7))*8)];
    }
  };
  auto MF = [&](int mb, int nb, bf16x8 (*bf)[2]){
    __builtin_amdgcn_s_setprio(1);
    #pragma unroll
    for (int m=0;m<4;m++)
      #pragma unroll
      for (int n=0;n<2;n++)
        #pragma unroll
        for (int kk=0;kk<2;kk++)
          acc[mb+m][nb+n] = __builtin_amdgcn_mfma_f32_16x16x32_bf16(
              aF[m][kk], bf[n][kk], acc[mb+m][nb+n], 0,0,0);
    __builtin_amdgcn_s_setprio(0);
  };

  // prologue: tile0 all 4 halves + Blo(1),Alo(1); vmcnt(4) completes tile0
  STG(A,  rA0, 0, 0, 0, 0);
  STG(A,  rA0, 0, 1, 0, 0);
  STG(BT, rB0, 0, 0, 0, 1);
  STG(BT, rB0, 0, 1, 0, 1);
  STG(BT, rB0, 1, 0, 1, 1);
  STG(A,  rA0, 1, 0, 1, 0);
  G8VW4();
  G8BAR();

  for (int kt = 0; kt < nkt; ++kt){
    int buf = kt & 1, nb = buf ^ 1;
    // ---- ph1 (m0-3 x n0-1): reads 12, stage Ahi(kt+1) ----
    if (kt + 1 < nkt) STG(A, rA0, kt+1, 1, nb, 0);
    RD_A(0, buf); RD_B(bF0, 0, buf);
    G8BAR();
    MF(0, 0, bF0);
    G8BAR();
    // ---- ph2 (m0-3 x n2-3): reads 4, stage Bhi(kt+1) ----
    if (kt + 1 < nkt) STG(BT, rB0, kt+1, 1, nb, 1);
    RD_B(bF1, 1, buf);
    G8BAR();
    MF(0, 2, bF1);
    G8BAR();
    // ---- ph3 (m4-7 x n0-1): reads 8, stage Blo(kt+2) into CURRENT buf ----
    if (kt + 2 < nkt) STG(BT, rB0, kt+2, 0, buf, 1);
    RD_A(1, buf);
    G8BAR();
    MF(4, 0, bF0);
    G8BAR();
    // ---- ph4 (m4-7 x n2-3): no reads, stage Alo(kt+2); tile-boundary wait ----
    if (kt + 2 < nkt) STG(A, rA0, kt+2, 0, buf, 0);
    G8BAR();
    MF(4, 2, bF1);
    if (kt == nkt-2) { G8VW0(); } else if (kt+1 < nkt) { G8VW4(); }
    G8BAR();
  }

  // GEGLU epilogue (a/g-interleaved WT, verified R9 mapping)
  float b1a[2], b1g[2];
  #pragma unroll
  for (int p=0;p<2;p++){
    int oc = (bn*8 + wn*2 + p)*16 + q15;
    b1a[p] = b1[oc];
    b1g[p] = b1[oc + 4096];
  }
  #pragma unroll
  for (int m=0;m<8;m++){
    int gr0 = bm*256 + wm*128 + m*16 + l16*4;
    #pragma unroll
    for (int p=0;p<2;p++){
      int ocol = (bn*8 + wn*2 + p)*16 + q15;
      #pragma unroll
      for (int j=0;j<4;j++){
        float va = acc[m][2*p][j]   + b1a[p];
        float vg = acc[m][2*p+1][j] + b1g[p];
        float f = va * (0.5f * vg * (1.f + erff(vg * 0.70710678118f)));
        Fout[(size_t)(gr0+j)*4096 + ocol] = f2bf(f);
      }
    }
  }
}

// ------------- V transpose: qkv (2048x3072) -> VT [16][64][2048] -------------
__global__ __launch_bounds__(256) void vtr_kernel(
    const unsigned short* __restrict__ qkv, unsigned short* __restrict__ VT)
{
  __shared__ unsigned int tile[64][33];
  int h = blockIdx.y;
  int n0 = blockIdx.x * 64;
  int t = threadIdx.x;
  #pragma unroll
  for (int p=0;p<8;p++){
    int idx = p*256 + t;
    int r = idx >> 5, c = idx & 31;
    tile[r][c] = *(const unsigned int*)(qkv + (size_t)(n0+r)*3072 + 2048 + h*64 + c*2);
  }
  __syncthreads();
  #pragma unroll
  for (int p=0;p<8;p++){
    int idx = p*256 + t;
    int d = idx >> 5, c = idx & 31;
    unsigned int a = tile[2*c][d>>1];
    unsigned int b = tile[2*c+1][d>>1];
    unsigned int lo = (d&1) ? (a>>16) : (a & 0xffffu);
    unsigned int hi = (d&1) ? (b>>16) : (b & 0xffffu);
    *(unsigned int*)(VT + (size_t)h*131072 + (size_t)d*2048 + n0 + c*2) = lo | (hi<<16);
  }
}

// ------- causal flash attention, MFMA, 64-q-row blocks, 2-phase dbuf ---------
__global__ __launch_bounds__(256) void flash_attn(
    const unsigned short* __restrict__ qkv,
    const unsigned short* __restrict__ VT,
    unsigned short* __restrict__ O)
{
  __shared__ unsigned short Klds[2][64*64];
  __shared__ unsigned short Vlds[2][64*64];
  __shared__ unsigned short Plds[4][16*72];
  __shared__ float fbuf[4][16];
  __shared__ float lbuf[4][16];

  int t = threadIdx.x;
  int lane = t & 63;
  int w = t >> 6;
  int q15 = lane & 15, l16 = lane >> 4;

  int bid = blockIdx.x;
  int x = bid & 7, r = bid >> 3;
  int h = 2*x + (r & 1);
  int q = r >> 1;
  int qt = (q < 16) ? q : 47 - q;
  int q0 = qt * 64;

  bf16x8 qF[2];
  int qrow = q0 + w*16 + q15;
  #pragma unroll
  for (int db=0; db<2; db++)
    qF[db] = *(const bf16x8*)(qkv + (size_t)qrow*3072 + h*64 + db*32 + l16*8);

  int srow = t >> 3, ssc = t & 7;
  auto STAGE = [&](int kt, int buf){
    int k0 = kt*64;
    #pragma unroll
    for (int c=0;c<2;c++){
      int row = c*32 + srow;
      int gc = ssc ^ (row & 7);
      const unsigned short* sk = qkv + (size_t)(k0+row)*3072 + 1024 + h*64 + gc*8;
      const unsigned short* sv = VT + (size_t)h*131072 + (size_t)row*2048 + k0 + gc*8;
      __builtin_amdgcn_global_load_lds(
        (const __attribute__((address_space(1))) unsigned int*)sk,
        (__attribute__((address_space(3))) unsigned int*)(&Klds[buf][(c*256 + (t & ~63))*8]),
        16, 0, 0);
      __builtin_amdgcn_global_load_lds(
        (const __attribute__((address_space(1))) unsigned int*)sv,
        (__attribute__((address_space(3))) unsigned int*)(&Vlds[buf][(c*256 + (t & ~63))*8]),
        16, 0, 0);
    }
  };

  f32x4 o[4] = {};
  float m_run = -1e30f, l_run = 0.f;

  STAGE(0, 0);
  __syncthreads();
  int cur = 0;
  for (int kt = 0; kt <= qt; ++kt){
    if (kt < qt) STAGE(kt + 1, cur ^ 1);

    f32x4 s[4] = {};
    #pragma unroll
    for (int km=0;km<4;km++){
      #pragma unroll
      for (int db=0;db<2;db++){
        int row = km*16 + q15;
        int ch = db*4 + l16;
        bf16x8 kF = *(const bf16x8*)&Klds[cur][row*64 + (ch ^ (row&7))*8];
        s[km] = __builtin_amdgcn_mfma_f32_16x16x32_bf16(kF, qF[db], s[km], 0,0,0);
      }
    }

    bool diag = (kt == qt);
    float pmax = -1e30f;
    #pragma unroll
    for (int km=0;km<4;km++){
      #pragma unroll
      for (int j=0;j<4;j++){
        float sv = s[km][j] * ATT_SCALE;
        if (diag){
          int kg = km*16 + l16*4 + j;
          int qg = w*16 + q15;
          if (kg > qg) sv = -1e30f;
        }
        s[km][j] = sv;
        pmax = fmaxf(pmax, sv);
      }
    }
    pmax = fmaxf(pmax, __shfl_xor(pmax, 16));
    pmax = fmaxf(pmax, __shfl_xor(pmax, 32));

    if (!__all(pmax - m_run <= 8.f)){
      float m_new = fmaxf(m_run, pmax);
      float f = __expf(m_run - m_new);
      m_run = m_new;
      l_run *= f;
      if (l16 == 0) fbuf[w][q15] = f;
      f32x4 fv = *(f32x4*)&fbuf[w][l16*4];
      #pragma unroll
      for (int n=0;n<4;n++) o[n] *= fv;
    }

    float lsum = 0.f;
    #pragma unroll
    for (int km=0;km<4;km++){
      float p0 = __expf(s[km][0]-m_run);
      float p1 = __expf(s[km][1]-m_run);
      float p2 = __expf(s[km][2]-m_run);
      float p3 = __expf(s[km][3]-m_run);
      lsum += (p0+p1)+(p2+p3);
      unsigned int v0 = (unsigned int)f2bf(p0) | ((unsigned int)f2bf(p1)<<16);
      unsigned int v1 = (unsigned int)f2bf(p2) | ((unsigned int)f2bf(p3)<<16);
      *(uint2*)&Plds[w][q15*72 + km*16 + l16*4] = make_uint2(v0,v1);
    }
    lsum += __shfl_xor(lsum,16);
    lsum += __shfl_xor(lsum,32);
    l_run += lsum;

    #pragma unroll
    for (int kb=0;kb<2;kb++){
      bf16x8 aP = *(const bf16x8*)&Plds[w][q15*72 + kb*32 + l16*8];
      #pragma unroll
      for (int n=0;n<4;n++){
        int row = n*16 + q15;
        int ch = kb*4 + l16;
        bf16x8 vF = *(const bf16x8*)&Vlds[cur][row*64 + (ch ^ (row&7))*8];
        o[n] = __builtin_amdgcn_mfma_f32_16x16x32_bf16(aP, vF, o[n], 0,0,0);
      }
    }
    __syncthreads();
    cur ^= 1;
  }

  if (l16 == 0) lbuf[w][q15] = 1.f / l_run;
  f32x4 lv = *(f32x4*)&lbuf[w][l16*4];

  #pragma unroll
  for (int n=0;n<4;n++){
    #pragma unroll
    for (int j=0;j<4;j++){
      int row = q0 + w*16 + l16*4 + j;
      int col = h*64 + n*16 + q15;
      O[(size_t)row*1024 + col] = f2bf(o[n][j]*lv[j]);
    }
  }
}

extern "C" void kernel_launch(void* const* d_in, const int* in_sizes, int n_in,
                              void* d_out, int out_size, void* d_ws, size_t ws_size,
                              hipStream_t stream)
{
  (void)in_sizes; (void)n_in; (void)out_size; (void)ws_size;
  const float* x_in = (const float*)d_in[0];
  const float* Wqkv = (const float*)d_in[2];
  const float* Wo   = (const float*)d_in[3];
  const float* bo   = (const float*)d_in[4];
  const float* ln1g = (const float*)d_in[5];
  const float* ln1b = (const float*)d_in[6];
  const float* ln2g = (const float*)d_in[7];
  const float* ln2b = (const float*)d_in[8];
  const float* ls1  = (const float*)d_in[9];
  const float* ls2  = (const float*)d_in[10];
  const float* W1   = (const float*)d_in[11];
  const float* b1   = (const float*)d_in[12];
  const float* W2   = (const float*)d_in[13];
  const float* b2   = (const float*)d_in[14];
  float* X = (float*)d_out;

  char* ws = (char*)d_ws;
  unsigned short* WTq = (unsigned short*)(ws);                 // 24 MiB
  unsigned short* WTo = (unsigned short*)(ws + (24u<<20));     // 8 MiB
  unsigned short* WT1 = (unsigned short*)(ws + (32u<<20));     // 64 MiB
  unsigned short* WT2 = (unsigned short*)(ws + (96u<<20));     // 32 MiB
  unsigned short* hb  = (unsigned short*)(ws + (128u<<20));    // 4 MiB
  unsigned short* qu  = (unsigned short*)(ws + (132u<<20));    // 12 MiB (qkv)
  unsigned short* VTg = (unsigned short*)(ws + (144u<<20));    // 4 MiB
  unsigned short* of  = (unsigned short*)(ws + (148u<<20));    // 16 MiB (o / F)
  unsigned short* PTb = (unsigned short*)(ws + (164u<<20));    // 32 MiB (bf16 SK partials)

  hipMemcpyAsync(d_out, (const void*)x_in, (size_t)2048*1024*4,
                 hipMemcpyDeviceToDevice, stream);

  trc_kernel<<<dim3(3072/64,1024/64,4),256,0,stream>>>(Wqkv, WTq, 1024, 3072);
  trc_kernel<<<dim3(1024/64,1024/64,4),256,0,stream>>>(Wo,   WTo, 1024, 1024);
  trc_w1_kernel<<<dim3(8192/64,1024/64,4),256,0,stream>>>(W1, WT1);
  trc_kernel<<<dim3(1024/64,4096/64,4),256,0,stream>>>(W2,   WT2, 4096, 1024);

  for (int l = 0; l < 4; ++l){
    // ---- attention sublayer ----
    if (l == 0)
      ln_kernel<<<2048,256,0,stream>>>(X, ln1g, ln1b, hb);
    gemm_bt<0,0><<<dim3(3072/128,2048/128),256,0,stream>>>(hb, WTq + (size_t)l*3072*1024,
        2048,3072,1024, qu, nullptr);
    vtr_kernel<<<dim3(32,16),256,0,stream>>>(qu, VTg);
    flash_attn<<<512,256,0,stream>>>(qu, VTg, of);
    gemm_bt<3,1><<<dim3(1024/128,2048/128,2),256,0,stream>>>(of, WTo + (size_t)l*1024*1024,
        2048,1024,1024, PTb, nullptr);
    redln_kernel<2,1><<<2048,256,0,stream>>>(PTb, X, bo + l*1024, ls1 + l*1024,
        ln2g + l*1024, ln2b + l*1024, hb);
    // ---- feedforward sublayer ----
    gemm8_w1<<<dim3(8192/256,2048/256),512,0,stream>>>(hb, WT1 + (size_t)l*8192*1024,
        of, b1 + (size_t)l*8192);
    gemm_bt<3,1><<<dim3(1024/128,2048/128,4),256,0,stream>>>(of, WT2 + (size_t)l*1024*4096,
        2048,1024,4096, PTb, nullptr);
    if (l < 3)
      redln_kernel<4,1><<<2048,256,0,stream>>>(PTb, X, b2 + l*1024, ls2 + l*1024,
          ln1g + (l+1)*1024, ln1b + (l+1)*1024, hb);
    else
      redln_kernel<4,0><<<2048,256,0,stream>>>(PTb, X, b2 + l*1024, ls2 + l*1024,
          nullptr, nullptr, nullptr);
  }
}